// Round 1
// baseline (455.131 us; speedup 1.0000x reference)
//
#include <hip/hip_runtime.h>
#include <math.h>

#define BATCH 16
#define CCH 256
#define LSEQ 4096
#define NB 4
#define CB 64           // channels per branch
#define MA_H 12         // moving-average half window (MA_K=25)
#define BN_EPS 1e-5f

// ---------------------------------------------------------------------------
// Kernel 1: per-branch dilated conv(k=3, zero pad) + BN(inference) + exact GELU
// grid (32 Ltiles, 4 branches, 16 batch), block 256
// writes h[B][C][L] (fp32) into workspace
// ---------------------------------------------------------------------------
__global__ __launch_bounds__(256) void k1_conv_bn_gelu(
    const float* __restrict__ x, const float* __restrict__ conv_w,
    const float* __restrict__ conv_b, const float* __restrict__ bn_gamma,
    const float* __restrict__ bn_beta, const float* __restrict__ bn_mean,
    const float* __restrict__ bn_var, float* __restrict__ h)
{
    const int tile  = blockIdx.x;      // 32 tiles of 128 positions
    const int br    = blockIdx.y;
    const int batch = blockIdx.z;
    const int d     = 1 << br;         // dilation 1,2,4,8
    const int t0    = tile * 128;
    const int tid   = threadIdx.x;

    __shared__ float xs[32][144];          // 32 in-ch x (128 + 2*d), d<=8
    __shared__ float wl[32 * 3 * 64];      // [r=(ii*3+k)][o]

    const int posgrp = tid & 31;           // 32 groups of 4 positions
    const int chgrp  = tid >> 5;           // 8 groups of 8 out channels
    const int o0     = chgrp * 8;

    float acc[8][4];
#pragma unroll
    for (int a = 0; a < 8; ++a)
#pragma unroll
        for (int q = 0; q < 4; ++q) acc[a][q] = 0.f;

    const int W = 128 + 2 * d;
    const float* xbase = x + ((size_t)(batch * CCH + br * CB)) * LSEQ;
    const float* wbase = conv_w + br * (CB * CB * 3);

    for (int ic0 = 0; ic0 < CB; ic0 += 32) {
        __syncthreads();
        // stage x rows [ic0, ic0+32), zero pad outside [0,L)
        for (int e = tid; e < 32 * W; e += 256) {
            int row = e / W;
            int col = e - row * W;
            int gt  = t0 - d + col;
            float v = 0.f;
            if (gt >= 0 && gt < LSEQ) v = xbase[(size_t)(ic0 + row) * LSEQ + gt];
            xs[row][col] = v;
        }
        // stage W transposed: wl[r][o], r = (i-ic0)*3 + k  (conflict-free LDS writes)
        for (int e = tid; e < 32 * 3 * 64; e += 256) {
            int o = e & 63;
            int r = e >> 6;
            wl[r * 64 + o] = wbase[o * 192 + ic0 * 3 + r];
        }
        __syncthreads();

#pragma unroll 2
        for (int ii = 0; ii < 32; ++ii) {
#pragma unroll
            for (int k = 0; k < 3; ++k) {
                const float* wp = &wl[(ii * 3 + k) * 64 + o0];
                float4 wa = *(const float4*)wp;
                float4 wb = *(const float4*)(wp + 4);
                float wv[8] = {wa.x, wa.y, wa.z, wa.w, wb.x, wb.y, wb.z, wb.w};
                float xv[4];
#pragma unroll
                for (int q = 0; q < 4; ++q)
                    xv[q] = xs[ii][posgrp * 4 + q + k * d];
#pragma unroll
                for (int a = 0; a < 8; ++a)
#pragma unroll
                    for (int q = 0; q < 4; ++q)
                        acc[a][q] = fmaf(wv[a], xv[q], acc[a][q]);
            }
        }
    }

    float* hbase = h + ((size_t)(batch * CCH + br * CB)) * LSEQ;
#pragma unroll
    for (int a = 0; a < 8; ++a) {
        int o = o0 + a;
        float bias = conv_b[br * CB + o];
        float inv  = rsqrtf(bn_var[br * CB + o] + BN_EPS);
        float sc   = bn_gamma[br * CB + o] * inv;
        float sh   = bn_beta[br * CB + o] - bn_mean[br * CB + o] * sc;
        float4 ov;
        float* po = (float*)&ov;
#pragma unroll
        for (int q = 0; q < 4; ++q) {
            float v = acc[a][q] + bias;
            v = v * sc + sh;
            po[q] = 0.5f * v * (1.f + erff(v * 0.70710678118654752f));  // exact gelu
        }
        *(float4*)&hbase[(size_t)o * LSEQ + t0 + posgrp * 4] = ov;
    }
}

// ---------------------------------------------------------------------------
// Kernel 2: 25-tap edge-padded moving average -> long; short = h - long;
// cumulative fuse (shorts forward, longs backward); writes fused[B][2C][L]
// grid (4 Ltiles of 1024, 64 j, 16 batch), block 256 (4 positions/thread)
// ---------------------------------------------------------------------------
__global__ __launch_bounds__(256) void k2_ma_fuse(
    const float* __restrict__ h, float* __restrict__ fused)
{
    const int tile   = blockIdx.x;
    const int j      = blockIdx.y;       // within-branch channel
    const int batch  = blockIdx.z;
    const int tstart = tile * 1024;
    const int tid    = threadIdx.x;

    __shared__ float hs[NB][1048];       // 1024 + 2*12 halo, edge-clamped

    for (int e = tid; e < NB * 1048; e += 256) {
        int row = e / 1048;
        int col = e - row * 1048;
        int gt  = tstart - MA_H + col;
        gt = max(0, min(LSEQ - 1, gt));
        hs[row][col] = h[((size_t)(batch * CCH + row * CB + j)) * LSEQ + gt];
    }
    __syncthreads();

    const int p0 = tstart + tid * 4;
    float sarr[NB][4], larr[NB][4];
#pragma unroll
    for (int br = 0; br < NB; ++br) {
        float r[28];
        const float4* rp = (const float4*)&hs[br][tid * 4];
#pragma unroll
        for (int q = 0; q < 7; ++q) {
            float4 v = rp[q];
            r[q * 4 + 0] = v.x; r[q * 4 + 1] = v.y;
            r[q * 4 + 2] = v.z; r[q * 4 + 3] = v.w;
        }
        float s = 0.f;
#pragma unroll
        for (int q = 0; q < 25; ++q) s += r[q];
        float l0 = s;
        float l1 = l0 - r[0] + r[25];
        float l2 = l1 - r[1] + r[26];
        float l3 = l2 - r[2] + r[27];
        const float inv25 = 1.f / 25.f;
        larr[br][0] = l0 * inv25; larr[br][1] = l1 * inv25;
        larr[br][2] = l2 * inv25; larr[br][3] = l3 * inv25;
#pragma unroll
        for (int q = 0; q < 4; ++q) sarr[br][q] = r[q + 12] - larr[br][q];
    }
#pragma unroll
    for (int b2 = 1; b2 < NB; ++b2)
#pragma unroll
        for (int q = 0; q < 4; ++q) sarr[b2][q] += sarr[b2 - 1][q];
#pragma unroll
    for (int b2 = NB - 2; b2 >= 0; --b2)
#pragma unroll
        for (int q = 0; q < 4; ++q) larr[b2][q] += larr[b2 + 1][q];

#pragma unroll
    for (int b2 = 0; b2 < NB; ++b2) {
        float4 sv = make_float4(sarr[b2][0], sarr[b2][1], sarr[b2][2], sarr[b2][3]);
        float4 lv = make_float4(larr[b2][0], larr[b2][1], larr[b2][2], larr[b2][3]);
        *(float4*)&fused[((size_t)(batch * 2 * CCH + b2 * CB + j)) * LSEQ + p0] = sv;
        *(float4*)&fused[((size_t)(batch * 2 * CCH + CCH + b2 * CB + j)) * LSEQ + p0] = lv;
    }
}

// ---------------------------------------------------------------------------
// Kernel 3: fusion 1x1 conv (GEMM M=256,K=512 per position) + bias + ReLU + alpha*x
// grid (32 Ltiles, 4 o-tiles of 64, 16 batch), block 256
// ---------------------------------------------------------------------------
__global__ __launch_bounds__(256) void k3_fusion(
    const float* __restrict__ fused, const float* __restrict__ fw,
    const float* __restrict__ fb, const float* __restrict__ x,
    const float* __restrict__ alpha, float* __restrict__ out)
{
    const int t0     = blockIdx.x * 128;
    const int o_base = blockIdx.y * 64;
    const int batch  = blockIdx.z;
    const int tid    = threadIdx.x;
    const int posgrp = tid & 31;   // 32 groups x 4 positions
    const int chgrp  = tid >> 5;   // 8 groups x 8 out channels

    __shared__ float fl[32][128];
    __shared__ float wlds[32][64];

    float acc[8][4];
#pragma unroll
    for (int a = 0; a < 8; ++a)
#pragma unroll
        for (int q = 0; q < 4; ++q) acc[a][q] = 0.f;

    for (int k0 = 0; k0 < 2 * CCH; k0 += 32) {
        __syncthreads();
#pragma unroll
        for (int n = 0; n < 4; ++n) {       // stage fused tile 32x128
            int e  = tid + n * 256;
            int kk = e >> 5, tq = e & 31;
            float4 v = *(const float4*)&fused[((size_t)(batch * 2 * CCH + k0 + kk)) * LSEQ + t0 + tq * 4];
            *(float4*)&fl[kk][tq * 4] = v;
        }
#pragma unroll
        for (int n = 0; n < 8; ++n) {       // stage W tile 64x32 -> [kk][o]
            int e  = tid + n * 256;
            int o  = e >> 5, kk = e & 31;
            wlds[kk][o] = fw[(size_t)(o_base + o) * (2 * CCH) + k0 + kk];
        }
        __syncthreads();

#pragma unroll 8
        for (int kk = 0; kk < 32; ++kk) {
            float4 xv = *(const float4*)&fl[kk][posgrp * 4];
            float4 wa = *(const float4*)&wlds[kk][chgrp * 8];
            float4 wb = *(const float4*)&wlds[kk][chgrp * 8 + 4];
            float wv[8] = {wa.x, wa.y, wa.z, wa.w, wb.x, wb.y, wb.z, wb.w};
            float xr[4] = {xv.x, xv.y, xv.z, xv.w};
#pragma unroll
            for (int a = 0; a < 8; ++a)
#pragma unroll
                for (int q = 0; q < 4; ++q)
                    acc[a][q] = fmaf(wv[a], xr[q], acc[a][q]);
        }
    }

    const float al = alpha[0];
#pragma unroll
    for (int a = 0; a < 8; ++a) {
        int o = o_base + chgrp * 8 + a;
        float bias = fb[o];
        size_t base = ((size_t)(batch * CCH + o)) * LSEQ + t0 + posgrp * 4;
        float4 xv = *(const float4*)&x[base];
        float4 ov;
        ov.x = fmaxf(acc[a][0] + bias, 0.f) + al * xv.x;
        ov.y = fmaxf(acc[a][1] + bias, 0.f) + al * xv.y;
        ov.z = fmaxf(acc[a][2] + bias, 0.f) + al * xv.z;
        ov.w = fmaxf(acc[a][3] + bias, 0.f) + al * xv.w;
        *(float4*)&out[base] = ov;
    }
}

// ---------------------------------------------------------------------------
extern "C" void kernel_launch(void* const* d_in, const int* in_sizes, int n_in,
                              void* d_out, int out_size, void* d_ws, size_t ws_size,
                              hipStream_t stream)
{
    const float* x        = (const float*)d_in[0];
    const float* conv_w   = (const float*)d_in[1];
    const float* conv_b   = (const float*)d_in[2];
    const float* bn_gamma = (const float*)d_in[3];
    const float* bn_beta  = (const float*)d_in[4];
    const float* bn_mean  = (const float*)d_in[5];
    const float* bn_var   = (const float*)d_in[6];
    const float* fw       = (const float*)d_in[7];
    const float* fb       = (const float*)d_in[8];
    const float* alpha    = (const float*)d_in[9];
    float* out = (float*)d_out;

    float* h     = (float*)d_ws;                                   // 64 MiB
    float* fused = (float*)((char*)d_ws + (size_t)BATCH * CCH * LSEQ * 4); // 128 MiB

    dim3 g1(32, NB, BATCH);
    k1_conv_bn_gelu<<<g1, 256, 0, stream>>>(x, conv_w, conv_b, bn_gamma, bn_beta,
                                            bn_mean, bn_var, h);
    dim3 g2(4, CB, BATCH);
    k2_ma_fuse<<<g2, 256, 0, stream>>>(h, fused);

    dim3 g3(32, CCH / 64, BATCH);
    k3_fusion<<<g3, 256, 0, stream>>>(fused, fw, fb, x, alpha, out);
}

// Round 3
// 238.546 us; speedup vs baseline: 1.9079x; 1.9079x over previous
//
#include <hip/hip_runtime.h>
#include <math.h>

#define BATCH 16
#define CCH 256
#define LSEQ 4096
#define NB 4
#define CB 64
#define MA_H 12
#define BN_EPS 1e-5f

typedef __attribute__((ext_vector_type(8))) short bf16x8;
typedef __attribute__((ext_vector_type(4))) float f32x4;

__device__ inline float b2f(ushort u) {
    union { uint i; float f; } v; v.i = ((uint)u) << 16; return v.f;
}
__device__ inline ushort f2b(float f) {   // round-to-nearest-even
    uint x = __float_as_uint(f);
    return (ushort)((x + 0x7FFFu + ((x >> 16) & 1u)) >> 16);
}

// ---------------------------------------------------------------------------
// Kernel 0: convert fusion weights fp32 [256][512] -> bf16
// ---------------------------------------------------------------------------
__global__ __launch_bounds__(256) void k0_convw(const float* __restrict__ fw,
                                                ushort* __restrict__ wbf)
{
    int i = (blockIdx.x * 256 + threadIdx.x) * 4;
    float4 v = *(const float4*)&fw[i];
    ushort4 o;
    o.x = f2b(v.x); o.y = f2b(v.y); o.z = f2b(v.z); o.w = f2b(v.w);
    *(ushort4*)&wbf[i] = o;
}

// ---------------------------------------------------------------------------
// Kernel 1: per-branch dilated conv(k=3) + BN + exact GELU -> h bf16 [B][C][L]
// ---------------------------------------------------------------------------
__global__ __launch_bounds__(256) void k1_conv_bn_gelu(
    const float* __restrict__ x, const float* __restrict__ conv_w,
    const float* __restrict__ conv_b, const float* __restrict__ bn_gamma,
    const float* __restrict__ bn_beta, const float* __restrict__ bn_mean,
    const float* __restrict__ bn_var, ushort* __restrict__ h)
{
    const int tile  = blockIdx.x;
    const int br    = blockIdx.y;
    const int batch = blockIdx.z;
    const int d     = 1 << br;
    const int t0    = tile * 128;
    const int tid   = threadIdx.x;

    __shared__ float xs[32][144];
    __shared__ float wl[32 * 3 * 64];

    const int posgrp = tid & 31;
    const int chgrp  = tid >> 5;
    const int o0     = chgrp * 8;

    float acc[8][4];
#pragma unroll
    for (int a = 0; a < 8; ++a)
#pragma unroll
        for (int q = 0; q < 4; ++q) acc[a][q] = 0.f;

    const int W = 128 + 2 * d;
    const float* xbase = x + ((size_t)(batch * CCH + br * CB)) * LSEQ;
    const float* wbase = conv_w + br * (CB * CB * 3);

    for (int ic0 = 0; ic0 < CB; ic0 += 32) {
        __syncthreads();
        for (int e = tid; e < 32 * W; e += 256) {
            int row = e / W;
            int col = e - row * W;
            int gt  = t0 - d + col;
            float v = 0.f;
            if (gt >= 0 && gt < LSEQ) v = xbase[(size_t)(ic0 + row) * LSEQ + gt];
            xs[row][col] = v;
        }
        for (int e = tid; e < 32 * 3 * 64; e += 256) {
            int o = e & 63;
            int r = e >> 6;
            wl[r * 64 + o] = wbase[o * 192 + ic0 * 3 + r];
        }
        __syncthreads();

#pragma unroll 2
        for (int ii = 0; ii < 32; ++ii) {
#pragma unroll
            for (int k = 0; k < 3; ++k) {
                const float* wp = &wl[(ii * 3 + k) * 64 + o0];
                float4 wa = *(const float4*)wp;
                float4 wb = *(const float4*)(wp + 4);
                float wv[8] = {wa.x, wa.y, wa.z, wa.w, wb.x, wb.y, wb.z, wb.w};
                float xv[4];
#pragma unroll
                for (int q = 0; q < 4; ++q)
                    xv[q] = xs[ii][posgrp * 4 + q + k * d];
#pragma unroll
                for (int a = 0; a < 8; ++a)
#pragma unroll
                    for (int q = 0; q < 4; ++q)
                        acc[a][q] = fmaf(wv[a], xv[q], acc[a][q]);
            }
        }
    }

    ushort* hbase = h + ((size_t)(batch * CCH + br * CB)) * LSEQ;
#pragma unroll
    for (int a = 0; a < 8; ++a) {
        int o = o0 + a;
        float bias = conv_b[br * CB + o];
        float inv  = rsqrtf(bn_var[br * CB + o] + BN_EPS);
        float sc   = bn_gamma[br * CB + o] * inv;
        float sh   = bn_beta[br * CB + o] - bn_mean[br * CB + o] * sc;
        ushort4 ov;
        ushort* po = (ushort*)&ov;
#pragma unroll
        for (int q = 0; q < 4; ++q) {
            float v = acc[a][q] + bias;
            v = v * sc + sh;
            po[q] = f2b(0.5f * v * (1.f + erff(v * 0.70710678118654752f)));
        }
        *(ushort4*)&hbase[(size_t)o * LSEQ + t0 + posgrp * 4] = ov;
    }
}

// ---------------------------------------------------------------------------
// Kernel 2: 25-tap edge-padded MA -> long; short = h - long; branch cumsum;
// writes TRANSPOSED fusedT[b][pos][512] bf16 (MFMA B-operand needs K-contig)
// grid (64 posTiles of 64, 1, 16 batch), block 256
// ---------------------------------------------------------------------------
#define HS_W 92        // 88 used + pad (184B rows: 8B-aligned, <=4-way banks)
__global__ __launch_bounds__(256) void k2_ma_fuse(
    const ushort* __restrict__ h, ushort* __restrict__ fusedT)
{
    const int t0    = blockIdx.x * 64;
    const int batch = blockIdx.z;
    const int tid   = threadIdx.x;

    __shared__ ushort hs[256][HS_W];

    // stage h[b][all 256 ch][t0-12 .. t0+75], edge-clamped, in 4-col chunks
    for (int e = tid; e < 256 * 22; e += 256) {
        int row = e / 22;
        int c4  = e - row * 22;
        int gt0 = t0 - MA_H + c4 * 4;
        const ushort* src = h + ((size_t)(batch * CCH + row)) * LSEQ;
        ushort4 v;
        if (gt0 >= 0 && gt0 + 3 < LSEQ) {
            v = *(const ushort4*)&src[gt0];
        } else {
            ushort* pv = (ushort*)&v;
#pragma unroll
            for (int q = 0; q < 4; ++q) {
                int gt = gt0 + q;
                gt = max(0, min(LSEQ - 1, gt));
                pv[q] = src[gt];
            }
        }
        *(ushort4*)&hs[row][c4 * 4] = v;
    }
    __syncthreads();

    const int j  = tid & 63;
    const int pg = tid >> 6;        // 4 groups x 16 positions
    const float inv25 = 1.f / 25.f;

#pragma unroll
    for (int p4 = 0; p4 < 4; ++p4) {
        const int p0 = pg * 16 + p4 * 4;   // window cols p0..p0+27
        float sarr[NB][4], larr[NB][4];
#pragma unroll
        for (int br = 0; br < NB; ++br) {
            const int c = br * CB + j;
            float r[28];
#pragma unroll
            for (int q = 0; q < 7; ++q) {
                ushort4 v = *(const ushort4*)&hs[c][p0 + q * 4];
                r[q * 4 + 0] = b2f(v.x); r[q * 4 + 1] = b2f(v.y);
                r[q * 4 + 2] = b2f(v.z); r[q * 4 + 3] = b2f(v.w);
            }
            float s = 0.f;
#pragma unroll
            for (int q = 0; q < 25; ++q) s += r[q];
            float l0 = s;
            float l1 = l0 - r[0] + r[25];
            float l2 = l1 - r[1] + r[26];
            float l3 = l2 - r[2] + r[27];
            larr[br][0] = l0 * inv25; larr[br][1] = l1 * inv25;
            larr[br][2] = l2 * inv25; larr[br][3] = l3 * inv25;
#pragma unroll
            for (int q = 0; q < 4; ++q) sarr[br][q] = r[q + 12] - larr[br][q];
        }
#pragma unroll
        for (int b2 = 1; b2 < NB; ++b2)
#pragma unroll
            for (int q = 0; q < 4; ++q) sarr[b2][q] += sarr[b2 - 1][q];
#pragma unroll
        for (int b2 = NB - 2; b2 >= 0; --b2)
#pragma unroll
            for (int q = 0; q < 4; ++q) larr[b2][q] += larr[b2 + 1][q];

#pragma unroll
        for (int q = 0; q < 4; ++q) {
            const int pos = t0 + p0 + q;
            ushort* dst = fusedT + ((size_t)(batch * LSEQ + pos)) * (2 * CCH);
#pragma unroll
            for (int b2 = 0; b2 < NB; ++b2) {
                dst[b2 * CB + j]       = f2b(sarr[b2][q]);
                dst[CCH + b2 * CB + j] = f2b(larr[b2][q]);
            }
        }
    }
}

// ---------------------------------------------------------------------------
// Kernel 3: fusion 1x1 conv as bf16 MFMA GEMM + bias + ReLU + alpha*x
// D[m=pos][n=o] = fusedT[pos][k] * W[k][o];  tile 128pos x 128o, BK=64
// grid (32 posTiles, 2 oTiles, 16 batch), block 256 (4 waves, 2x2)
// ---------------------------------------------------------------------------
#define KTOT 512
#define SA 72          // padded LDS row stride (144B: 16B-aligned, 2-way banks)
__global__ __launch_bounds__(256) void k3_fusion(
    const ushort* __restrict__ fusedT, const ushort* __restrict__ wbf,
    const float* __restrict__ fb, const float* __restrict__ x,
    const float* __restrict__ alpha, float* __restrict__ out)
{
    const int t0    = blockIdx.x * 128;
    const int oBase = blockIdx.y * 128;
    const int batch = blockIdx.z;
    const int tid   = threadIdx.x;
    const int wid   = tid >> 6;
    const int lane  = tid & 63;
    const int lo    = lane & 15;
    const int hi    = lane >> 4;
    const int wm    = wid >> 1;     // pos-half
    const int wn    = wid & 1;      // o-half

    __shared__ short AL[128 * SA];  // fusedT tile [128 pos][64 k]
    __shared__ short WL[128 * SA];  // W tile      [128 o  ][64 k]

    f32x4 acc[4][4];
#pragma unroll
    for (int mi = 0; mi < 4; ++mi)
#pragma unroll
        for (int ni = 0; ni < 4; ++ni) acc[mi][ni] = (f32x4)0.f;

    const int srow = tid >> 3;      // 32 rows per pass
    const int scol = tid & 7;       // 8 x 16B chunks (8 ushorts each) per row

    for (int k0 = 0; k0 < KTOT; k0 += 64) {
        __syncthreads();
#pragma unroll
        for (int pass = 0; pass < 4; ++pass) {
            int row = pass * 32 + srow;
            uint4 va = *(const uint4*)&fusedT[
                ((size_t)(batch * LSEQ + t0 + row)) * (2 * CCH) + k0 + scol * 8];
            *(uint4*)&AL[row * SA + scol * 8] = va;
            uint4 vw = *(const uint4*)&wbf[
                (size_t)(oBase + row) * KTOT + k0 + scol * 8];
            *(uint4*)&WL[row * SA + scol * 8] = vw;
        }
        __syncthreads();

#pragma unroll
        for (int ks = 0; ks < 2; ++ks) {
            bf16x8 af[4], bfr[4];
#pragma unroll
            for (int mi = 0; mi < 4; ++mi)
                af[mi] = *(const bf16x8*)&AL[(wm * 64 + mi * 16 + lo) * SA + ks * 32 + hi * 8];
#pragma unroll
            for (int ni = 0; ni < 4; ++ni)
                bfr[ni] = *(const bf16x8*)&WL[(wn * 64 + ni * 16 + lo) * SA + ks * 32 + hi * 8];
#pragma unroll
            for (int mi = 0; mi < 4; ++mi)
#pragma unroll
                for (int ni = 0; ni < 4; ++ni)
                    acc[mi][ni] = __builtin_amdgcn_mfma_f32_16x16x32_bf16(
                        af[mi], bfr[ni], acc[mi][ni], 0, 0, 0);
        }
    }

    const float al = alpha[0];
#pragma unroll
    for (int ni = 0; ni < 4; ++ni) {
        const int o = oBase + wn * 64 + ni * 16 + lo;
        const float bias = fb[o];
#pragma unroll
        for (int mi = 0; mi < 4; ++mi) {
            const int pos = t0 + wm * 64 + mi * 16 + hi * 4;
            size_t base = ((size_t)(batch * CCH + o)) * LSEQ + pos;
            float4 xv = *(const float4*)&x[base];
            float4 ov;
            ov.x = fmaxf(acc[mi][ni][0] + bias, 0.f) + al * xv.x;
            ov.y = fmaxf(acc[mi][ni][1] + bias, 0.f) + al * xv.y;
            ov.z = fmaxf(acc[mi][ni][2] + bias, 0.f) + al * xv.z;
            ov.w = fmaxf(acc[mi][ni][3] + bias, 0.f) + al * xv.w;
            *(float4*)&out[base] = ov;
        }
    }
}

// ---------------------------------------------------------------------------
extern "C" void kernel_launch(void* const* d_in, const int* in_sizes, int n_in,
                              void* d_out, int out_size, void* d_ws, size_t ws_size,
                              hipStream_t stream)
{
    const float* x        = (const float*)d_in[0];
    const float* conv_w   = (const float*)d_in[1];
    const float* conv_b   = (const float*)d_in[2];
    const float* bn_gamma = (const float*)d_in[3];
    const float* bn_beta  = (const float*)d_in[4];
    const float* bn_mean  = (const float*)d_in[5];
    const float* bn_var   = (const float*)d_in[6];
    const float* fw       = (const float*)d_in[7];
    const float* fb       = (const float*)d_in[8];
    const float* alpha    = (const float*)d_in[9];
    float* out = (float*)d_out;

    ushort* h      = (ushort*)d_ws;                                     // 32 MiB
    ushort* fusedT = (ushort*)((char*)d_ws + (size_t)32 * 1024 * 1024); // 64 MiB
    ushort* wbf    = (ushort*)((char*)d_ws + (size_t)96 * 1024 * 1024); // 256 KiB

    k0_convw<<<dim3(128), 256, 0, stream>>>(fw, wbf);

    dim3 g1(32, NB, BATCH);
    k1_conv_bn_gelu<<<g1, 256, 0, stream>>>(x, conv_w, conv_b, bn_gamma, bn_beta,
                                            bn_mean, bn_var, h);
    dim3 g2(64, 1, BATCH);
    k2_ma_fuse<<<g2, 256, 0, stream>>>(h, fusedT);

    dim3 g3(32, 2, BATCH);
    k3_fusion<<<g3, 256, 0, stream>>>(fusedT, wbf, fb, x, alpha, out);
}

// Round 4
// 149.549 us; speedup vs baseline: 3.0433x; 1.5951x over previous
//
#include <hip/hip_runtime.h>
#include <math.h>

#define BATCH 16
#define CCH 256
#define LSEQ 4096
#define NB 4
#define CB 64
#define MA_H 12
#define BN_EPS 1e-5f

typedef __attribute__((ext_vector_type(8))) short bf16x8;
typedef __attribute__((ext_vector_type(4))) float f32x4;

__device__ inline float b2f(ushort u) {
    union { uint i; float f; } v; v.i = ((uint)u) << 16; return v.f;
}
__device__ inline ushort f2b(float f) {   // round-to-nearest-even
    uint x = __float_as_uint(f);
    return (ushort)((x + 0x7FFFu + ((x >> 16) & 1u)) >> 16);
}

// ---------------------------------------------------------------------------
// Kernel 0: convert fusion weights fp32 [256][512] -> bf16
// ---------------------------------------------------------------------------
__global__ __launch_bounds__(256) void k0_convw(const float* __restrict__ fw,
                                                ushort* __restrict__ wbf)
{
    int i = (blockIdx.x * 256 + threadIdx.x) * 4;
    float4 v = *(const float4*)&fw[i];
    ushort4 o;
    o.x = f2b(v.x); o.y = f2b(v.y); o.z = f2b(v.z); o.w = f2b(v.w);
    *(ushort4*)&wbf[i] = o;
}

// ---------------------------------------------------------------------------
// Kernel 0b: reorder branch conv weights [br][o][i][kk] fp32
//            -> wbr[br][o][kk*64+i] bf16  (K-major for MFMA B fragments)
// ---------------------------------------------------------------------------
__global__ __launch_bounds__(256) void k0b_convw_branch(
    const float* __restrict__ conv_w, ushort* __restrict__ wbr)
{
    int e = blockIdx.x * 256 + threadIdx.x;     // 4*64*3*64 = 49152
    int i    = e & 63;
    int rest = e >> 6;            // br*192 + o*3 + kk  (0..767)
    int kk   = rest % 3;
    int orow = rest / 3;          // br*64 + o  (0..255)
    float v = conv_w[(size_t)orow * 192 + i * 3 + kk];
    wbr[(size_t)orow * 192 + kk * 64 + i] = f2b(v);
}

// ---------------------------------------------------------------------------
// Kernel 1: per-branch dilated conv(k=3) as bf16 MFMA GEMM + BN + exact GELU
// D[m=pos][n=o] = sum_{k=kk*64+i} x[i][pos+(kk-1)d] * w[o][kk*64+i]
// grid (32 posTiles of 128, 4 branches, 16 batch), block 256 (4 waves)
// ---------------------------------------------------------------------------
#define SXA 72     // LDS stride for x-tile rows (144B, 16B-aligned, uniform banks)
#define SWB 200    // LDS stride for w rows (400B, 16B-aligned, uniform banks)
__global__ __launch_bounds__(256) void k1_conv_mfma(
    const float* __restrict__ x, const ushort* __restrict__ wbr,
    const float* __restrict__ conv_b, const float* __restrict__ bn_gamma,
    const float* __restrict__ bn_beta, const float* __restrict__ bn_mean,
    const float* __restrict__ bn_var, ushort* __restrict__ h)
{
    const int tile  = blockIdx.x;
    const int br    = blockIdx.y;
    const int batch = blockIdx.z;
    const int d     = 1 << br;
    const int t0    = tile * 128;
    const int tid   = threadIdx.x;
    const int wm    = tid >> 6;      // wave -> pos quarter (32 pos)
    const int lane  = tid & 63;
    const int lo    = lane & 15;
    const int hi    = lane >> 4;

    __shared__ ushort xsA[144 * SXA];   // x^T tile: [local pos 0..143][64 ch]
    __shared__ ushort wlB[64 * SWB];    // w tile:   [64 o][192 k]

    // ---- stage A: transpose x[ch][pos] -> xsA[pos][ch], zero-pad edges ----
    {
        const int ch   = tid & 63;
        const int pgrp = tid >> 6;                  // 4 groups x 36 pos
        const float* xrow = x + ((size_t)(batch * CCH + br * CB + ch)) * LSEQ;
        const int base = t0 - 8 + pgrp * 36;
#pragma unroll
        for (int c4 = 0; c4 < 9; ++c4) {
            int gp0 = base + c4 * 4;
            float4 v;
            if (gp0 >= 0 && gp0 <= LSEQ - 4) {
                v = *(const float4*)&xrow[gp0];
            } else {
                float* pv = (float*)&v;
#pragma unroll
                for (int q = 0; q < 4; ++q) {
                    int gp = gp0 + q;
                    pv[q] = (gp >= 0 && gp < LSEQ) ? xrow[gp] : 0.f;
                }
            }
            int r = pgrp * 36 + c4 * 4;
            xsA[(r + 0) * SXA + ch] = f2b(v.x);
            xsA[(r + 1) * SXA + ch] = f2b(v.y);
            xsA[(r + 2) * SXA + ch] = f2b(v.z);
            xsA[(r + 3) * SXA + ch] = f2b(v.w);
        }
    }
    // ---- stage B: wbr[br][o][192] -> wlB[o][192] (linear uint4) ----
    {
        const int o     = tid & 63;
        const int cbase = tid >> 6;
        const ushort* wrow = wbr + ((size_t)(br * CB + o)) * 192;
#pragma unroll
        for (int it = 0; it < 6; ++it) {
            int chunk = cbase + it * 4;             // 0..23
            uint4 v = *(const uint4*)&wrow[chunk * 8];
            *(uint4*)&wlB[o * SWB + chunk * 8] = v;
        }
    }
    __syncthreads();

    f32x4 acc[2][4];
#pragma unroll
    for (int mi = 0; mi < 2; ++mi)
#pragma unroll
        for (int ni = 0; ni < 4; ++ni) acc[mi][ni] = (f32x4)0.f;

#pragma unroll
    for (int kk = 0; kk < 3; ++kk) {
        const int roff = 8 + (kk - 1) * d;          // 0..16
#pragma unroll
        for (int ks = 0; ks < 2; ++ks) {
            bf16x8 af[2], bfr[4];
#pragma unroll
            for (int mi = 0; mi < 2; ++mi)
                af[mi] = *(const bf16x8*)&xsA[
                    (wm * 32 + mi * 16 + lo + roff) * SXA + ks * 32 + hi * 8];
#pragma unroll
            for (int ni = 0; ni < 4; ++ni)
                bfr[ni] = *(const bf16x8*)&wlB[
                    (ni * 16 + lo) * SWB + kk * 64 + ks * 32 + hi * 8];
#pragma unroll
            for (int mi = 0; mi < 2; ++mi)
#pragma unroll
                for (int ni = 0; ni < 4; ++ni)
                    acc[mi][ni] = __builtin_amdgcn_mfma_f32_16x16x32_bf16(
                        af[mi], bfr[ni], acc[mi][ni], 0, 0, 0);
        }
    }

    // ---- epilogue: bias + BN + exact GELU -> h bf16 [B][C][L] ----
    ushort* hbase = h + ((size_t)(batch * CCH + br * CB)) * LSEQ;
#pragma unroll
    for (int ni = 0; ni < 4; ++ni) {
        const int o  = ni * 16 + lo;
        const int go = br * CB + o;
        float bias = conv_b[go];
        float inv  = rsqrtf(bn_var[go] + BN_EPS);
        float sc   = bn_gamma[go] * inv;
        float sh   = bn_beta[go] - bn_mean[go] * sc;
#pragma unroll
        for (int mi = 0; mi < 2; ++mi) {
            const int pos = t0 + wm * 32 + mi * 16 + hi * 4;
            ushort4 ov;
            ushort* po = (ushort*)&ov;
#pragma unroll
            for (int q = 0; q < 4; ++q) {
                float v = acc[mi][ni][q] + bias;
                v = v * sc + sh;
                po[q] = f2b(0.5f * v * (1.f + erff(v * 0.70710678118654752f)));
            }
            *(ushort4*)&hbase[(size_t)o * LSEQ + pos] = ov;
        }
    }
}

// ---------------------------------------------------------------------------
// Kernel 2: 25-tap edge-padded MA -> long; short = h - long; branch cumsum;
// writes TRANSPOSED fusedT[b][pos][512] bf16 (MFMA B-operand needs K-contig)
// grid (64 posTiles of 64, 1, 16 batch), block 256
// ---------------------------------------------------------------------------
#define HS_W 92        // 88 used + pad (184B rows: 8B-aligned, <=4-way banks)
__global__ __launch_bounds__(256) void k2_ma_fuse(
    const ushort* __restrict__ h, ushort* __restrict__ fusedT)
{
    const int t0    = blockIdx.x * 64;
    const int batch = blockIdx.z;
    const int tid   = threadIdx.x;

    __shared__ ushort hs[256][HS_W];

    for (int e = tid; e < 256 * 22; e += 256) {
        int row = e / 22;
        int c4  = e - row * 22;
        int gt0 = t0 - MA_H + c4 * 4;
        const ushort* src = h + ((size_t)(batch * CCH + row)) * LSEQ;
        ushort4 v;
        if (gt0 >= 0 && gt0 + 3 < LSEQ) {
            v = *(const ushort4*)&src[gt0];
        } else {
            ushort* pv = (ushort*)&v;
#pragma unroll
            for (int q = 0; q < 4; ++q) {
                int gt = gt0 + q;
                gt = max(0, min(LSEQ - 1, gt));
                pv[q] = src[gt];
            }
        }
        *(ushort4*)&hs[row][c4 * 4] = v;
    }
    __syncthreads();

    const int j  = tid & 63;
    const int pg = tid >> 6;
    const float inv25 = 1.f / 25.f;

#pragma unroll
    for (int p4 = 0; p4 < 4; ++p4) {
        const int p0 = pg * 16 + p4 * 4;
        float sarr[NB][4], larr[NB][4];
#pragma unroll
        for (int br = 0; br < NB; ++br) {
            const int c = br * CB + j;
            float r[28];
#pragma unroll
            for (int q = 0; q < 7; ++q) {
                ushort4 v = *(const ushort4*)&hs[c][p0 + q * 4];
                r[q * 4 + 0] = b2f(v.x); r[q * 4 + 1] = b2f(v.y);
                r[q * 4 + 2] = b2f(v.z); r[q * 4 + 3] = b2f(v.w);
            }
            float s = 0.f;
#pragma unroll
            for (int q = 0; q < 25; ++q) s += r[q];
            float l0 = s;
            float l1 = l0 - r[0] + r[25];
            float l2 = l1 - r[1] + r[26];
            float l3 = l2 - r[2] + r[27];
            larr[br][0] = l0 * inv25; larr[br][1] = l1 * inv25;
            larr[br][2] = l2 * inv25; larr[br][3] = l3 * inv25;
#pragma unroll
            for (int q = 0; q < 4; ++q) sarr[br][q] = r[q + 12] - larr[br][q];
        }
#pragma unroll
        for (int b2 = 1; b2 < NB; ++b2)
#pragma unroll
            for (int q = 0; q < 4; ++q) sarr[b2][q] += sarr[b2 - 1][q];
#pragma unroll
        for (int b2 = NB - 2; b2 >= 0; --b2)
#pragma unroll
            for (int q = 0; q < 4; ++q) larr[b2][q] += larr[b2 + 1][q];

#pragma unroll
        for (int q = 0; q < 4; ++q) {
            const int pos = t0 + p0 + q;
            ushort* dst = fusedT + ((size_t)(batch * LSEQ + pos)) * (2 * CCH);
#pragma unroll
            for (int b2 = 0; b2 < NB; ++b2) {
                dst[b2 * CB + j]       = f2b(sarr[b2][q]);
                dst[CCH + b2 * CB + j] = f2b(larr[b2][q]);
            }
        }
    }
}

// ---------------------------------------------------------------------------
// Kernel 3: fusion 1x1 conv as bf16 MFMA GEMM + bias + ReLU + alpha*x
// ---------------------------------------------------------------------------
#define KTOT 512
#define SA 72
__global__ __launch_bounds__(256) void k3_fusion(
    const ushort* __restrict__ fusedT, const ushort* __restrict__ wbf,
    const float* __restrict__ fb, const float* __restrict__ x,
    const float* __restrict__ alpha, float* __restrict__ out)
{
    const int t0    = blockIdx.x * 128;
    const int oBase = blockIdx.y * 128;
    const int batch = blockIdx.z;
    const int tid   = threadIdx.x;
    const int wid   = tid >> 6;
    const int lane  = tid & 63;
    const int lo    = lane & 15;
    const int hi    = lane >> 4;
    const int wm    = wid >> 1;
    const int wn    = wid & 1;

    __shared__ short AL[128 * SA];
    __shared__ short WL[128 * SA];

    f32x4 acc[4][4];
#pragma unroll
    for (int mi = 0; mi < 4; ++mi)
#pragma unroll
        for (int ni = 0; ni < 4; ++ni) acc[mi][ni] = (f32x4)0.f;

    const int srow = tid >> 3;
    const int scol = tid & 7;

    for (int k0 = 0; k0 < KTOT; k0 += 64) {
        __syncthreads();
#pragma unroll
        for (int pass = 0; pass < 4; ++pass) {
            int row = pass * 32 + srow;
            uint4 va = *(const uint4*)&fusedT[
                ((size_t)(batch * LSEQ + t0 + row)) * (2 * CCH) + k0 + scol * 8];
            *(uint4*)&AL[row * SA + scol * 8] = va;
            uint4 vw = *(const uint4*)&wbf[
                (size_t)(oBase + row) * KTOT + k0 + scol * 8];
            *(uint4*)&WL[row * SA + scol * 8] = vw;
        }
        __syncthreads();

#pragma unroll
        for (int ks = 0; ks < 2; ++ks) {
            bf16x8 af[4], bfr[4];
#pragma unroll
            for (int mi = 0; mi < 4; ++mi)
                af[mi] = *(const bf16x8*)&AL[(wm * 64 + mi * 16 + lo) * SA + ks * 32 + hi * 8];
#pragma unroll
            for (int ni = 0; ni < 4; ++ni)
                bfr[ni] = *(const bf16x8*)&WL[(wn * 64 + ni * 16 + lo) * SA + ks * 32 + hi * 8];
#pragma unroll
            for (int mi = 0; mi < 4; ++mi)
#pragma unroll
                for (int ni = 0; ni < 4; ++ni)
                    acc[mi][ni] = __builtin_amdgcn_mfma_f32_16x16x32_bf16(
                        af[mi], bfr[ni], acc[mi][ni], 0, 0, 0);
        }
    }

    const float al = alpha[0];
#pragma unroll
    for (int ni = 0; ni < 4; ++ni) {
        const int o = oBase + wn * 64 + ni * 16 + lo;
        const float bias = fb[o];
#pragma unroll
        for (int mi = 0; mi < 4; ++mi) {
            const int pos = t0 + wm * 64 + mi * 16 + hi * 4;
            size_t base = ((size_t)(batch * CCH + o)) * LSEQ + pos;
            float4 xv = *(const float4*)&x[base];
            float4 ov;
            ov.x = fmaxf(acc[mi][ni][0] + bias, 0.f) + al * xv.x;
            ov.y = fmaxf(acc[mi][ni][1] + bias, 0.f) + al * xv.y;
            ov.z = fmaxf(acc[mi][ni][2] + bias, 0.f) + al * xv.z;
            ov.w = fmaxf(acc[mi][ni][3] + bias, 0.f) + al * xv.w;
            *(float4*)&out[base] = ov;
        }
    }
}

// ---------------------------------------------------------------------------
extern "C" void kernel_launch(void* const* d_in, const int* in_sizes, int n_in,
                              void* d_out, int out_size, void* d_ws, size_t ws_size,
                              hipStream_t stream)
{
    const float* x        = (const float*)d_in[0];
    const float* conv_w   = (const float*)d_in[1];
    const float* conv_b   = (const float*)d_in[2];
    const float* bn_gamma = (const float*)d_in[3];
    const float* bn_beta  = (const float*)d_in[4];
    const float* bn_mean  = (const float*)d_in[5];
    const float* bn_var   = (const float*)d_in[6];
    const float* fw       = (const float*)d_in[7];
    const float* fb       = (const float*)d_in[8];
    const float* alpha    = (const float*)d_in[9];
    float* out = (float*)d_out;

    ushort* h      = (ushort*)d_ws;                                     // 32 MiB
    ushort* fusedT = (ushort*)((char*)d_ws + (size_t)32 * 1024 * 1024); // 64 MiB
    ushort* wbf    = (ushort*)((char*)d_ws + (size_t)96 * 1024 * 1024); // 256 KiB
    ushort* wbr    = (ushort*)((char*)d_ws + (size_t)97 * 1024 * 1024); // 96 KiB

    k0_convw<<<dim3(128), 256, 0, stream>>>(fw, wbf);
    k0b_convw_branch<<<dim3(192), 256, 0, stream>>>(conv_w, wbr);

    dim3 g1(32, NB, BATCH);
    k1_conv_mfma<<<g1, 256, 0, stream>>>(x, wbr, conv_b, bn_gamma, bn_beta,
                                         bn_mean, bn_var, h);
    dim3 g2(64, 1, BATCH);
    k2_ma_fuse<<<g2, 256, 0, stream>>>(h, fusedT);

    dim3 g3(32, 2, BATCH);
    k3_fusion<<<g3, 256, 0, stream>>>(fusedT, wbf, fb, x, alpha, out);
}

// Round 5
// 141.895 us; speedup vs baseline: 3.2075x; 1.0539x over previous
//
#include <hip/hip_runtime.h>
#include <math.h>

#define BATCH 16
#define CCH 256
#define LSEQ 4096
#define NB 4
#define CB 64
#define MA_H 12
#define BN_EPS 1e-5f

typedef __attribute__((ext_vector_type(8))) short bf16x8;
typedef __attribute__((ext_vector_type(4))) float f32x4;

__device__ inline float b2f(ushort u) {
    union { uint i; float f; } v; v.i = ((uint)u) << 16; return v.f;
}
__device__ inline ushort f2b(float f) {   // round-to-nearest-even
    uint x = __float_as_uint(f);
    return (ushort)((x + 0x7FFFu + ((x >> 16) & 1u)) >> 16);
}

// ---------------------------------------------------------------------------
// Kernel 0: convert fusion weights fp32 [256][512] -> bf16
// ---------------------------------------------------------------------------
__global__ __launch_bounds__(256) void k0_convw(const float* __restrict__ fw,
                                                ushort* __restrict__ wbf)
{
    int i = (blockIdx.x * 256 + threadIdx.x) * 4;
    float4 v = *(const float4*)&fw[i];
    ushort4 o;
    o.x = f2b(v.x); o.y = f2b(v.y); o.z = f2b(v.z); o.w = f2b(v.w);
    *(ushort4*)&wbf[i] = o;
}

// ---------------------------------------------------------------------------
// Kernel 0b: reorder branch conv weights [br][o][i][kk] fp32
//            -> wbr[br][o][kk*64+i] bf16  (K-major for MFMA B fragments)
// ---------------------------------------------------------------------------
__global__ __launch_bounds__(256) void k0b_convw_branch(
    const float* __restrict__ conv_w, ushort* __restrict__ wbr)
{
    int e = blockIdx.x * 256 + threadIdx.x;     // 4*64*3*64 = 49152
    int i    = e & 63;
    int rest = e >> 6;            // br*192 + o*3 + kk  (0..767)
    int kk   = rest % 3;
    int orow = rest / 3;          // br*64 + o  (0..255)
    float v = conv_w[(size_t)orow * 192 + i * 3 + kk];
    wbr[(size_t)orow * 192 + kk * 64 + i] = f2b(v);
}

// ---------------------------------------------------------------------------
// Kernel 1: per-branch dilated conv(k=3) as bf16 MFMA GEMM + BN + exact GELU
// D[m=pos][n=o] = sum_{k=kk*64+i} x[i][pos+(kk-1)d] * w[o][kk*64+i]
// grid (32 posTiles of 128, 4 branches, 16 batch), block 256 (4 waves)
// A-tile stored [ch][pos] (coalesced staging); frags via scalar u16 reads.
// ---------------------------------------------------------------------------
#define SXP 180    // LDS pos-stride for x rows (360B: 8B-aligned, 2-way banks)
#define SWB 200    // LDS stride for w rows (400B, 16B-aligned, uniform banks)
__global__ __launch_bounds__(256) void k1_conv_mfma(
    const float* __restrict__ x, const ushort* __restrict__ wbr,
    const float* __restrict__ conv_b, const float* __restrict__ bn_gamma,
    const float* __restrict__ bn_beta, const float* __restrict__ bn_mean,
    const float* __restrict__ bn_var, ushort* __restrict__ h)
{
    const int tile  = blockIdx.x;
    const int br    = blockIdx.y;
    const int batch = blockIdx.z;
    const int d     = 1 << br;
    const int t0    = tile * 128;
    const int tid   = threadIdx.x;
    const int wm    = tid >> 6;      // wave -> pos quarter (32 pos)
    const int lane  = tid & 63;
    const int lo    = lane & 15;
    const int hi    = lane >> 4;

    __shared__ ushort xsA[64 * SXP];    // x tile: [64 ch][pos 0..143 used]
    __shared__ ushort wlB[64 * SWB];    // w tile: [64 o][192 k]

    // ---- stage A: coalesced along pos; bf16; [ch][pos]; zero-pad edges ----
    {
        const float* xbase = x + ((size_t)(batch * CCH + br * CB)) * LSEQ;
#pragma unroll
        for (int pass = 0; pass < 9; ++pass) {
            int e  = tid + pass * 256;          // < 64*36
            int ch = e / 36;
            int c4 = e - ch * 36;
            int gp0 = t0 - 8 + c4 * 4;
            float4 v;
            if (gp0 >= 0 && gp0 + 3 < LSEQ) {
                v = *(const float4*)&xbase[(size_t)ch * LSEQ + gp0];
            } else {
                float* pv = (float*)&v;
#pragma unroll
                for (int q = 0; q < 4; ++q) {
                    int gp = gp0 + q;
                    pv[q] = (gp >= 0 && gp < LSEQ) ? xbase[(size_t)ch * LSEQ + gp] : 0.f;
                }
            }
            ushort4 o4;
            o4.x = f2b(v.x); o4.y = f2b(v.y); o4.z = f2b(v.z); o4.w = f2b(v.w);
            *(ushort4*)&xsA[ch * SXP + c4 * 4] = o4;      // 8B write, 8B-aligned
        }
    }
    // ---- stage B: linear coalesced uint4; wlB[o][192] padded ----
    {
        const ushort* wrow = wbr + ((size_t)br * CB) * 192;
#pragma unroll
        for (int pass = 0; pass < 6; ++pass) {
            int e = tid + pass * 256;           // < 64*24
            int o = e / 24;
            int c = e - o * 24;
            uint4 v = *(const uint4*)&wrow[e * 8];        // fully linear global
            *(uint4*)&wlB[o * SWB + c * 8] = v;           // 16B-aligned
        }
    }
    __syncthreads();

    f32x4 acc[2][4];
#pragma unroll
    for (int mi = 0; mi < 2; ++mi)
#pragma unroll
        for (int ni = 0; ni < 4; ++ni) acc[mi][ni] = (f32x4)0.f;

#pragma unroll
    for (int kk = 0; kk < 3; ++kk) {
        const int roff = 8 + (kk - 1) * d;          // 0..16
#pragma unroll
        for (int ks = 0; ks < 2; ++ks) {
            bf16x8 af[2], bfr[4];
#pragma unroll
            for (int mi = 0; mi < 2; ++mi) {
                const int p = wm * 32 + mi * 16 + lo + roff;
                uint u[4];
#pragma unroll
                for (int jp = 0; jp < 4; ++jp) {
                    ushort e0 = xsA[(ks * 32 + hi * 8 + jp * 2 + 0) * SXP + p];
                    ushort e1 = xsA[(ks * 32 + hi * 8 + jp * 2 + 1) * SXP + p];
                    u[jp] = (uint)e0 | ((uint)e1 << 16);
                }
                union { uint ui[4]; bf16x8 bv; } cvt;
                cvt.ui[0] = u[0]; cvt.ui[1] = u[1];
                cvt.ui[2] = u[2]; cvt.ui[3] = u[3];
                af[mi] = cvt.bv;
            }
#pragma unroll
            for (int ni = 0; ni < 4; ++ni)
                bfr[ni] = *(const bf16x8*)&wlB[
                    (ni * 16 + lo) * SWB + kk * 64 + ks * 32 + hi * 8];
#pragma unroll
            for (int mi = 0; mi < 2; ++mi)
#pragma unroll
                for (int ni = 0; ni < 4; ++ni)
                    acc[mi][ni] = __builtin_amdgcn_mfma_f32_16x16x32_bf16(
                        af[mi], bfr[ni], acc[mi][ni], 0, 0, 0);
        }
    }

    // ---- epilogue: bias + BN + exact GELU -> h bf16 [B][C][L] ----
    ushort* hbase = h + ((size_t)(batch * CCH + br * CB)) * LSEQ;
#pragma unroll
    for (int ni = 0; ni < 4; ++ni) {
        const int o  = ni * 16 + lo;
        const int go = br * CB + o;
        float bias = conv_b[go];
        float inv  = rsqrtf(bn_var[go] + BN_EPS);
        float sc   = bn_gamma[go] * inv;
        float sh   = bn_beta[go] - bn_mean[go] * sc;
#pragma unroll
        for (int mi = 0; mi < 2; ++mi) {
            const int pos = t0 + wm * 32 + mi * 16 + hi * 4;
            ushort4 ov;
            ushort* po = (ushort*)&ov;
#pragma unroll
            for (int q = 0; q < 4; ++q) {
                float v = acc[mi][ni][q] + bias;
                v = v * sc + sh;
                po[q] = f2b(0.5f * v * (1.f + erff(v * 0.70710678118654752f)));
            }
            *(ushort4*)&hbase[(size_t)o * LSEQ + pos] = ov;
        }
    }
}

// ---------------------------------------------------------------------------
// Kernel 2: 25-tap edge-padded MA -> long; short = h - long; branch cumsum;
// writes TRANSPOSED fusedT[b][pos][512] bf16 (MFMA B-operand needs K-contig)
// grid (64 posTiles of 64, 1, 16 batch), block 256
// ---------------------------------------------------------------------------
#define HS_W 92        // 88 used + pad (184B rows: 8B-aligned, <=4-way banks)
__global__ __launch_bounds__(256) void k2_ma_fuse(
    const ushort* __restrict__ h, ushort* __restrict__ fusedT)
{
    const int t0    = blockIdx.x * 64;
    const int batch = blockIdx.z;
    const int tid   = threadIdx.x;

    __shared__ ushort hs[256][HS_W];

    for (int e = tid; e < 256 * 22; e += 256) {
        int row = e / 22;
        int c4  = e - row * 22;
        int gt0 = t0 - MA_H + c4 * 4;
        const ushort* src = h + ((size_t)(batch * CCH + row)) * LSEQ;
        ushort4 v;
        if (gt0 >= 0 && gt0 + 3 < LSEQ) {
            v = *(const ushort4*)&src[gt0];
        } else {
            ushort* pv = (ushort*)&v;
#pragma unroll
            for (int q = 0; q < 4; ++q) {
                int gt = gt0 + q;
                gt = max(0, min(LSEQ - 1, gt));
                pv[q] = src[gt];
            }
        }
        *(ushort4*)&hs[row][c4 * 4] = v;
    }
    __syncthreads();

    const int j  = tid & 63;
    const int pg = tid >> 6;
    const float inv25 = 1.f / 25.f;

#pragma unroll
    for (int p4 = 0; p4 < 4; ++p4) {
        const int p0 = pg * 16 + p4 * 4;
        float sarr[NB][4], larr[NB][4];
#pragma unroll
        for (int br = 0; br < NB; ++br) {
            const int c = br * CB + j;
            float r[28];
#pragma unroll
            for (int q = 0; q < 7; ++q) {
                ushort4 v = *(const ushort4*)&hs[c][p0 + q * 4];
                r[q * 4 + 0] = b2f(v.x); r[q * 4 + 1] = b2f(v.y);
                r[q * 4 + 2] = b2f(v.z); r[q * 4 + 3] = b2f(v.w);
            }
            float s = 0.f;
#pragma unroll
            for (int q = 0; q < 25; ++q) s += r[q];
            float l0 = s;
            float l1 = l0 - r[0] + r[25];
            float l2 = l1 - r[1] + r[26];
            float l3 = l2 - r[2] + r[27];
            larr[br][0] = l0 * inv25; larr[br][1] = l1 * inv25;
            larr[br][2] = l2 * inv25; larr[br][3] = l3 * inv25;
#pragma unroll
            for (int q = 0; q < 4; ++q) sarr[br][q] = r[q + 12] - larr[br][q];
        }
#pragma unroll
        for (int b2 = 1; b2 < NB; ++b2)
#pragma unroll
            for (int q = 0; q < 4; ++q) sarr[b2][q] += sarr[b2 - 1][q];
#pragma unroll
        for (int b2 = NB - 2; b2 >= 0; --b2)
#pragma unroll
            for (int q = 0; q < 4; ++q) larr[b2][q] += larr[b2 + 1][q];

#pragma unroll
        for (int q = 0; q < 4; ++q) {
            const int pos = t0 + p0 + q;
            ushort* dst = fusedT + ((size_t)(batch * LSEQ + pos)) * (2 * CCH);
#pragma unroll
            for (int b2 = 0; b2 < NB; ++b2) {
                dst[b2 * CB + j]       = f2b(sarr[b2][q]);
                dst[CCH + b2 * CB + j] = f2b(larr[b2][q]);
            }
        }
    }
}

// ---------------------------------------------------------------------------
// Kernel 3: fusion 1x1 conv as bf16 MFMA GEMM + bias + ReLU + alpha*x
// ---------------------------------------------------------------------------
#define KTOT 512
#define SA 72
__global__ __launch_bounds__(256) void k3_fusion(
    const ushort* __restrict__ fusedT, const ushort* __restrict__ wbf,
    const float* __restrict__ fb, const float* __restrict__ x,
    const float* __restrict__ alpha, float* __restrict__ out)
{
    const int t0    = blockIdx.x * 128;
    const int oBase = blockIdx.y * 128;
    const int batch = blockIdx.z;
    const int tid   = threadIdx.x;
    const int wid   = tid >> 6;
    const int lane  = tid & 63;
    const int lo    = lane & 15;
    const int hi    = lane >> 4;
    const int wm    = wid >> 1;
    const int wn    = wid & 1;

    __shared__ short AL[128 * SA];
    __shared__ short WL[128 * SA];

    f32x4 acc[4][4];
#pragma unroll
    for (int mi = 0; mi < 4; ++mi)
#pragma unroll
        for (int ni = 0; ni < 4; ++ni) acc[mi][ni] = (f32x4)0.f;

    const int srow = tid >> 3;
    const int scol = tid & 7;

    for (int k0 = 0; k0 < KTOT; k0 += 64) {
        __syncthreads();
#pragma unroll
        for (int pass = 0; pass < 4; ++pass) {
            int row = pass * 32 + srow;
            uint4 va = *(const uint4*)&fusedT[
                ((size_t)(batch * LSEQ + t0 + row)) * (2 * CCH) + k0 + scol * 8];
            *(uint4*)&AL[row * SA + scol * 8] = va;
            uint4 vw = *(const uint4*)&wbf[
                (size_t)(oBase + row) * KTOT + k0 + scol * 8];
            *(uint4*)&WL[row * SA + scol * 8] = vw;
        }
        __syncthreads();

#pragma unroll
        for (int ks = 0; ks < 2; ++ks) {
            bf16x8 af[4], bfr[4];
#pragma unroll
            for (int mi = 0; mi < 4; ++mi)
                af[mi] = *(const bf16x8*)&AL[(wm * 64 + mi * 16 + lo) * SA + ks * 32 + hi * 8];
#pragma unroll
            for (int ni = 0; ni < 4; ++ni)
                bfr[ni] = *(const bf16x8*)&WL[(wn * 64 + ni * 16 + lo) * SA + ks * 32 + hi * 8];
#pragma unroll
            for (int mi = 0; mi < 4; ++mi)
#pragma unroll
                for (int ni = 0; ni < 4; ++ni)
                    acc[mi][ni] = __builtin_amdgcn_mfma_f32_16x16x32_bf16(
                        af[mi], bfr[ni], acc[mi][ni], 0, 0, 0);
        }
    }

    const float al = alpha[0];
#pragma unroll
    for (int ni = 0; ni < 4; ++ni) {
        const int o = oBase + wn * 64 + ni * 16 + lo;
        const float bias = fb[o];
#pragma unroll
        for (int mi = 0; mi < 4; ++mi) {
            const int pos = t0 + wm * 64 + mi * 16 + hi * 4;
            size_t base = ((size_t)(batch * CCH + o)) * LSEQ + pos;
            float4 xv = *(const float4*)&x[base];
            float4 ov;
            ov.x = fmaxf(acc[mi][ni][0] + bias, 0.f) + al * xv.x;
            ov.y = fmaxf(acc[mi][ni][1] + bias, 0.f) + al * xv.y;
            ov.z = fmaxf(acc[mi][ni][2] + bias, 0.f) + al * xv.z;
            ov.w = fmaxf(acc[mi][ni][3] + bias, 0.f) + al * xv.w;
            *(float4*)&out[base] = ov;
        }
    }
}

// ---------------------------------------------------------------------------
extern "C" void kernel_launch(void* const* d_in, const int* in_sizes, int n_in,
                              void* d_out, int out_size, void* d_ws, size_t ws_size,
                              hipStream_t stream)
{
    const float* x        = (const float*)d_in[0];
    const float* conv_w   = (const float*)d_in[1];
    const float* conv_b   = (const float*)d_in[2];
    const float* bn_gamma = (const float*)d_in[3];
    const float* bn_beta  = (const float*)d_in[4];
    const float* bn_mean  = (const float*)d_in[5];
    const float* bn_var   = (const float*)d_in[6];
    const float* fw       = (const float*)d_in[7];
    const float* fb       = (const float*)d_in[8];
    const float* alpha    = (const float*)d_in[9];
    float* out = (float*)d_out;

    ushort* h      = (ushort*)d_ws;                                     // 32 MiB
    ushort* fusedT = (ushort*)((char*)d_ws + (size_t)32 * 1024 * 1024); // 64 MiB
    ushort* wbf    = (ushort*)((char*)d_ws + (size_t)96 * 1024 * 1024); // 256 KiB
    ushort* wbr    = (ushort*)((char*)d_ws + (size_t)97 * 1024 * 1024); // 96 KiB

    k0_convw<<<dim3(128), 256, 0, stream>>>(fw, wbf);
    k0b_convw_branch<<<dim3(192), 256, 0, stream>>>(conv_w, wbr);

    dim3 g1(32, NB, BATCH);
    k1_conv_mfma<<<g1, 256, 0, stream>>>(x, wbr, conv_b, bn_gamma, bn_beta,
                                         bn_mean, bn_var, h);
    dim3 g2(64, 1, BATCH);
    k2_ma_fuse<<<g2, 256, 0, stream>>>(h, fusedT);

    dim3 g3(32, 2, BATCH);
    k3_fusion<<<g3, 256, 0, stream>>>(fusedT, wbf, fb, x, alpha, out);
}